// Round 2
// baseline (906.434 us; speedup 1.0000x reference)
//
#include <hip/hip_runtime.h>
#include <math.h>

// Problem constants (fixed by reference)
#define NR 2048
#define MC 131072
#define DIM 64
#define KSEL 11                    // k+1 smallest kept per row
#define PPART 64                   // column partitions
#define PART_COLS (MC / PPART)     // 2048 cols per partition
#define CHUNK 128                  // cols per LDS chunk
#define NCHUNK (PART_COLS / CHUNK) // 16
#define CAP 38                     // per-row candidate bucket capacity
#define BKSTR 39                   // bucket row stride (dwords); 39 mod 32 = 7, coprime -> conflict-free owner scan
#define BSTRIDE 72                 // padded f16 row stride in LDS

typedef _Float16 v8h __attribute__((ext_vector_type(8)));
typedef float v4f __attribute__((ext_vector_type(4)));

// ---------------- prep: bnorm (fp32) + buf -> f16 ----------------
__global__ __launch_bounds__(256) void k_prep_b(const float* __restrict__ buf,
                                                _Float16* __restrict__ B16,
                                                float* __restrict__ bnorm) {
  int gid = blockIdx.x * 256 + threadIdx.x;   // 4 threads per buffer row
  int row = gid >> 2, q = gid & 3;
  const float4* src = (const float4*)(buf + (size_t)row * DIM + q * 16);
  float4 f0 = src[0], f1 = src[1], f2 = src[2], f3 = src[3];
  float s = f0.x*f0.x + f0.y*f0.y + f0.z*f0.z + f0.w*f0.w
          + f1.x*f1.x + f1.y*f1.y + f1.z*f1.z + f1.w*f1.w
          + f2.x*f2.x + f2.y*f2.y + f2.z*f2.z + f2.w*f2.w
          + f3.x*f3.x + f3.y*f3.y + f3.z*f3.z + f3.w*f3.w;
  s += __shfl_xor(s, 1);
  s += __shfl_xor(s, 2);
  if (q == 0) bnorm[row] = s;
  union { _Float16 h[16]; uint4 u[2]; } o;
  o.h[0]=(_Float16)f0.x; o.h[1]=(_Float16)f0.y; o.h[2]=(_Float16)f0.z; o.h[3]=(_Float16)f0.w;
  o.h[4]=(_Float16)f1.x; o.h[5]=(_Float16)f1.y; o.h[6]=(_Float16)f1.z; o.h[7]=(_Float16)f1.w;
  o.h[8]=(_Float16)f2.x; o.h[9]=(_Float16)f2.y; o.h[10]=(_Float16)f2.z; o.h[11]=(_Float16)f2.w;
  o.h[12]=(_Float16)f3.x; o.h[13]=(_Float16)f3.y; o.h[14]=(_Float16)f3.z; o.h[15]=(_Float16)f3.w;
  uint4* dst = (uint4*)(B16 + (size_t)row * DIM + q * 16);
  dst[0] = o.u[0]; dst[1] = o.u[1];
}

// ---------------- scan pass: ballot-compacted candidate push (no atomics) ----
// Value group (ct,rt,reg): each quad-group of 16 lanes holds 16 columns of one
// row. Ballot gives every lane its write position and the (uniform-in-group)
// count increment -- counts live in registers, identical across the 16 lanes.
template<bool CHK>
__device__ __forceinline__ void scan_pass(
    const v4f acc[2][8], const float bnr[8], const float* thr_w,
    const float xn[2][4], float* bucket_w, int cnt[8],
    unsigned long long& done, int quad,
    unsigned long long gmask, unsigned long long ltmask)
{
  float thrx[2][4];
#pragma unroll
  for (int rt = 0; rt < 2; ++rt)
#pragma unroll
    for (int reg = 0; reg < 4; ++reg)
      thrx[rt][reg] = thr_w[rt * 16 + quad * 4 + reg] - xn[rt][reg];
#pragma unroll
  for (int ct = 0; ct < 8; ++ct) {
    float bn = bnr[ct];
#pragma unroll
    for (int rt = 0; rt < 2; ++rt)
#pragma unroll
      for (int reg = 0; reg < 4; ++reg) {
        const int g = rt * 4 + reg;
        const int b = ct * 8 + g;
        float t = fmaf(acc[rt][ct][reg], -2.0f, bn);   // bn - 2*dot
        bool p = t < thrx[rt][reg];                    // d2 < thr  <=>  t < thr - xn
        if (CHK) p = p && !((done >> b) & 1ULL);
        unsigned long long m = __ballot(p);
        if (m) {                                       // wave-uniform skip
          unsigned long long mg = m & gmask;
          if (p) {
            int idx = cnt[g] + __popcll(mg & ltmask);
            if (idx < CAP) {
              bucket_w[(rt * 16 + quad * 4 + reg) * BKSTR + idx] =
                  fmaxf(t + xn[rt][reg], 0.0f);
              done |= 1ULL << b;
            }
          }
          cnt[g] += __popcll(mg);
        }
      }
  }
}

// ---------------- drain: owner lanes fold bucket into register top-11 --------
__device__ __forceinline__ void drain_update(
    int lane, int quad, int cnt[8],
    float* bucket_w, int* bcnt_w, float* thr_w,
    float lst[KSEL], float& lmax, int& amax)
{
  if ((lane & 15) == 0) {   // one lane per quad publishes its 8 row counts
    int4 c0, c1;
    c0.x = min(cnt[0], CAP); c0.y = min(cnt[1], CAP);
    c0.z = min(cnt[2], CAP); c0.w = min(cnt[3], CAP);
    c1.x = min(cnt[4], CAP); c1.y = min(cnt[5], CAP);
    c1.z = min(cnt[6], CAP); c1.w = min(cnt[7], CAP);
    *(int4*)&bcnt_w[quad * 4] = c0;
    *(int4*)&bcnt_w[16 + quad * 4] = c1;
  }
  __builtin_amdgcn_s_waitcnt(0);   // wave-local LDS visibility (cross-lane)
  if (lane < 32) {
    int n = bcnt_w[lane];
    const float* bk = &bucket_w[lane * BKSTR];
    for (int i = 0; i < n; ++i) {
      float vv = bk[i];
      if (vv < lmax) {
#pragma unroll
        for (int j = 0; j < KSEL; ++j) if (j == amax) lst[j] = vv;
        lmax = lst[0]; amax = 0;
#pragma unroll
        for (int j = 1; j < KSEL; ++j) if (lst[j] > lmax) { lmax = lst[j]; amax = j; }
      }
    }
    thr_w[lane] = lmax;
  }
  __builtin_amdgcn_s_waitcnt(0);
#pragma unroll
  for (int g = 0; g < 8; ++g) cnt[g] = 0;
}

// ---------------- main: MFMA d2 tiles + ballot top-11 ----------------
// grid (PPART, NR/128); wave w owns 32 rows; selection is wave-local.
__global__ __launch_bounds__(256) void k_main(const float* __restrict__ x,
                                              const _Float16* __restrict__ B16,
                                              const float* __restrict__ bnorm,
                                              float* __restrict__ cand) {
  __shared__ __align__(16) _Float16 Bs[CHUNK * BSTRIDE];   // 18432 B
  __shared__ float bns[CHUNK];                             //   512 B
  __shared__ float thr_s[4][32];                           //   512 B
  __shared__ float bucket[4][32 * BKSTR];                  // 19968 B
  __shared__ int bcnt[4][32];                              //   512 B  -> 39936 B total

  const int tid = threadIdx.x;
  const int w = tid >> 6, lane = tid & 63;
  const int quad = lane >> 4, l15 = lane & 15;
  const int rowbase = blockIdx.y * 128 + w * 32;
  const int pbase = blockIdx.x * PART_COLS;
  const unsigned long long gmask = 0xFFFFULL << (quad * 16);
  const unsigned long long ltmask = (1ULL << lane) - 1ULL;

  if (lane < 32) thr_s[w][lane] = __builtin_inff();

  // A fragments (f16) + row norms computed in-kernel (prep_x folded in).
  // A layout (16x16x32): A[m = lane&15][k = quad*8 + j]
  v8h afrag[2][2];
  float nrm[2];
#pragma unroll
  for (int rt = 0; rt < 2; ++rt) {
    const float* xr = x + (size_t)(rowbase + rt * 16 + l15) * DIM;
    float s = 0.0f;
#pragma unroll
    for (int ks = 0; ks < 2; ++ks) {
      const float4* xp = (const float4*)(xr + ks * 32 + quad * 8);
      float4 a0 = xp[0], a1 = xp[1];
      v8h h;
      h[0]=(_Float16)a0.x; h[1]=(_Float16)a0.y; h[2]=(_Float16)a0.z; h[3]=(_Float16)a0.w;
      h[4]=(_Float16)a1.x; h[5]=(_Float16)a1.y; h[6]=(_Float16)a1.z; h[7]=(_Float16)a1.w;
      afrag[rt][ks] = h;
      s += a0.x*a0.x + a0.y*a0.y + a0.z*a0.z + a0.w*a0.w
         + a1.x*a1.x + a1.y*a1.y + a1.z*a1.z + a1.w*a1.w;
    }
    s += __shfl_xor(s, 16);   // sum across the 4 quads holding this row
    s += __shfl_xor(s, 32);
    nrm[rt] = s;              // norm of row rt*16 + l15
  }
  float xn[2][4];             // norms in C-layout: row = quad*4 + reg
#pragma unroll
  for (int rt = 0; rt < 2; ++rt)
#pragma unroll
    for (int reg = 0; reg < 4; ++reg)
      xn[rt][reg] = __shfl(nrm[rt], quad * 4 + reg);

  float lst[KSEL];
#pragma unroll
  for (int i = 0; i < KSEL; ++i) lst[i] = __builtin_inff();
  float lmax = __builtin_inff();
  int amax = 0;
  int cnt[8];
#pragma unroll
  for (int g = 0; g < 8; ++g) cnt[g] = 0;

  for (int c = 0; c < NCHUNK; ++c) {
    const int cb = pbase + c * CHUNK;
    __syncthreads();   // Bs free
    {
      int brow = tid >> 1, hf = tid & 1;   // 2 threads per col, 32 f16 each
      const uint4* src = (const uint4*)(B16 + (size_t)(cb + brow) * DIM + hf * 32);
      uint4 v0 = src[0], v1 = src[1], v2 = src[2], v3 = src[3];
      uint4* dst = (uint4*)(Bs + brow * BSTRIDE + hf * 32);
      dst[0] = v0; dst[1] = v1; dst[2] = v2; dst[3] = v3;
      if (tid < CHUNK) bns[tid] = bnorm[cb + tid];
    }
    __syncthreads();   // staged

    float bnr[8];
#pragma unroll
    for (int ct = 0; ct < 8; ++ct) bnr[ct] = bns[ct * 16 + l15];

    v4f acc[2][8];
#pragma unroll
    for (int rt = 0; rt < 2; ++rt)
#pragma unroll
      for (int ct = 0; ct < 8; ++ct) acc[rt][ct] = (v4f)(0.0f);
#pragma unroll
    for (int ct = 0; ct < 8; ++ct) {
      v8h b0 = *(const v8h*)(Bs + (ct * 16 + l15) * BSTRIDE + quad * 8);
      v8h b1 = *(const v8h*)(Bs + (ct * 16 + l15) * BSTRIDE + 32 + quad * 8);
      acc[0][ct] = __builtin_amdgcn_mfma_f32_16x16x32_f16(afrag[0][0], b0, acc[0][ct], 0, 0, 0);
      acc[0][ct] = __builtin_amdgcn_mfma_f32_16x16x32_f16(afrag[0][1], b1, acc[0][ct], 0, 0, 0);
      acc[1][ct] = __builtin_amdgcn_mfma_f32_16x16x32_f16(afrag[1][0], b0, acc[1][ct], 0, 0, 0);
      acc[1][ct] = __builtin_amdgcn_mfma_f32_16x16x32_f16(afrag[1][1], b1, acc[1][ct], 0, 0, 0);
    }

    unsigned long long done = 0ULL;
    scan_pass<false>(acc, bnr, thr_s[w], xn, bucket[w], cnt, done, quad, gmask, ltmask);
    for (int it = 0; it < 8; ++it) {
      int mx = cnt[0];
#pragma unroll
      for (int g = 1; g < 8; ++g) mx = max(mx, cnt[g]);
      unsigned long long om = __ballot(mx > CAP);   // overflow anywhere in wave?
      drain_update(lane, quad, cnt, bucket[w], bcnt[w], thr_s[w], lst, lmax, amax);
      if (!om) break;
      scan_pass<true>(acc, bnr, thr_s[w], xn, bucket[w], cnt, done, quad, gmask, ltmask);
    }
  }

  if (lane < 32) {
    int grow = rowbase + lane;
#pragma unroll
    for (int i = 0; i < KSEL; ++i)
      cand[((size_t)(blockIdx.x * KSEL + i)) * NR + grow] = lst[i];   // [p][k][row]
  }
}

// ---------------- merge: 64x11 candidates -> top-11 -> output ----------------
__global__ __launch_bounds__(64) void k_merge(const float* __restrict__ cand,
                                              float* __restrict__ out) {
  int row = blockIdx.x * 64 + threadIdx.x;
  float lst[KSEL];
#pragma unroll
  for (int i = 0; i < KSEL; ++i) lst[i] = __builtin_inff();
  float lmax = __builtin_inff();
  int amax = 0;
  for (int pi = 0; pi < PPART * KSEL; ++pi) {
    float vv = cand[(size_t)pi * NR + row];   // coalesced across rows
    if (vv < lmax) {
#pragma unroll
      for (int j = 0; j < KSEL; ++j) if (j == amax) lst[j] = vv;
      lmax = lst[0]; amax = 0;
#pragma unroll
      for (int j = 1; j < KSEL; ++j) if (lst[j] > lmax) { lmax = lst[j]; amax = j; }
    }
  }
  float vmin = lst[0];
#pragma unroll
  for (int j = 1; j < KSEL; ++j) vmin = fminf(vmin, lst[j]);
  float s = 0.0f;
#pragma unroll
  for (int j = 0; j < KSEL; ++j) s += sqrtf(lst[j]);
  s -= sqrtf(vmin);                 // drop the self-match
  out[row] = log1pf(s * 0.1f);      // mean over k=10, log1p
}

extern "C" void kernel_launch(void* const* d_in, const int* in_sizes, int n_in,
                              void* d_out, int out_size, void* d_ws, size_t ws_size,
                              hipStream_t stream) {
  (void)in_sizes; (void)n_in; (void)out_size; (void)ws_size;
  const float* x   = (const float*)d_in[0];   // 2048 x 64
  const float* buf = (const float*)d_in[1];   // 131072 x 64
  float* out = (float*)d_out;

  char* ws = (char*)d_ws;
  _Float16* B16 = (_Float16*)ws;                       // 16,777,216 B
  float* bnorm  = (float*)(ws + 16777216);             //    524,288 B
  float* cand   = (float*)(ws + 17301504);             //  5,767,168 B

  k_prep_b<<<dim3(2048), dim3(256), 0, stream>>>(buf, B16, bnorm);
  k_main<<<dim3(PPART, NR / 128), dim3(256), 0, stream>>>(x, B16, bnorm, cand);
  k_merge<<<dim3(NR / 64), dim3(64), 0, stream>>>(cand, out);
}

// Round 4
// 324.152 us; speedup vs baseline: 2.7963x; 2.7963x over previous
//
#include <hip/hip_runtime.h>
#include <math.h>

// Problem constants (fixed by reference)
#define NR 2048
#define MC 131072
#define DIM 64
#define KSEL 11                    // k+1 smallest kept per row
#define PPART 64                   // column partitions
#define PART_COLS (MC / PPART)     // 2048 cols per partition
#define CHUNK 128                  // cols per LDS chunk
#define NCHUNK (PART_COLS / CHUNK) // 16
#define ROWS_PER_BLOCK 64          // 4 waves x 16 rows
#define QCAP 32                    // per-lane queue capacity (= max pushes/chunk)
#define QSTR 33                    // queue stride: bank = (lane+i)%32, conflict-free
#define BSTRIDE 72                 // padded f16 col stride in LDS (144B)

typedef _Float16 v8h __attribute__((ext_vector_type(8)));
typedef float v4f __attribute__((ext_vector_type(4)));

// ---------------- prep: bnorm (fp32) + buf -> f16 ----------------
__global__ __launch_bounds__(256) void k_prep_b(const float* __restrict__ buf,
                                                _Float16* __restrict__ B16,
                                                float* __restrict__ bnorm) {
  int gid = blockIdx.x * 256 + threadIdx.x;   // 4 threads per buffer row
  int row = gid >> 2, q = gid & 3;
  const float4* src = (const float4*)(buf + (size_t)row * DIM + q * 16);
  float4 f0 = src[0], f1 = src[1], f2 = src[2], f3 = src[3];
  float s = f0.x*f0.x + f0.y*f0.y + f0.z*f0.z + f0.w*f0.w
          + f1.x*f1.x + f1.y*f1.y + f1.z*f1.z + f1.w*f1.w
          + f2.x*f2.x + f2.y*f2.y + f2.z*f2.z + f2.w*f2.w
          + f3.x*f3.x + f3.y*f3.y + f3.z*f3.z + f3.w*f3.w;
  s += __shfl_xor(s, 1);
  s += __shfl_xor(s, 2);
  if (q == 0) bnorm[row] = s;
  union { _Float16 h[16]; uint4 u[2]; } o;
  o.h[0]=(_Float16)f0.x; o.h[1]=(_Float16)f0.y; o.h[2]=(_Float16)f0.z; o.h[3]=(_Float16)f0.w;
  o.h[4]=(_Float16)f1.x; o.h[5]=(_Float16)f1.y; o.h[6]=(_Float16)f1.z; o.h[7]=(_Float16)f1.w;
  o.h[8]=(_Float16)f2.x; o.h[9]=(_Float16)f2.y; o.h[10]=(_Float16)f2.z; o.h[11]=(_Float16)f2.w;
  o.h[12]=(_Float16)f3.x; o.h[13]=(_Float16)f3.y; o.h[14]=(_Float16)f3.z; o.h[15]=(_Float16)f3.w;
  uint4* dst = (uint4*)(B16 + (size_t)row * DIM + q * 16);
  dst[0] = o.u[0]; dst[1] = o.u[1];
}

// insert v into unsorted 11-list; caller guarantees v < lmax
__device__ __forceinline__ void ins11(float v, float* lst, float& lmax) {
  bool done = false;
#pragma unroll
  for (int j = 0; j < KSEL; ++j) {
    bool m = (!done) && (lst[j] == lmax);   // replace one copy of the max
    lst[j] = m ? v : lst[j];
    done = done || m;
  }
  float a = fmaxf(fmaxf(lst[0], lst[1]), fmaxf(lst[2], lst[3]));
  float b = fmaxf(fmaxf(lst[4], lst[5]), fmaxf(lst[6], lst[7]));
  float c = fmaxf(fmaxf(lst[8], lst[9]), lst[10]);
  lmax = fmaxf(fmaxf(a, b), c);
}

// ---------------- main: swapped-operand MFMA + per-lane top-11 ----------------
// D = A(bufcols) x B(xrows): C-layout gives each lane ONE x-row (n = lane&15),
// 4 bufcols per m-tile (m = quad*4+reg). Selection is fully lane-private:
// register list + private LDS queue; threshold shared across quads via shfl.
__global__ __launch_bounds__(256) void k_main(const float* __restrict__ x,
                                              const _Float16* __restrict__ B16,
                                              const float* __restrict__ bnorm,
                                              float* __restrict__ cand) {
  __shared__ __align__(16) _Float16 Bs[CHUNK * BSTRIDE];   // 18432 B
  __shared__ float bns[CHUNK];                             //   512 B
  __shared__ float qmem[4][64 * QSTR];                     // 33792 B -> 52736 B

  const int tid = threadIdx.x;
  const int w = tid >> 6, lane = tid & 63;
  const int quad = lane >> 4, l15 = lane & 15;
  const int row = blockIdx.y * ROWS_PER_BLOCK + w * 16 + l15;  // this lane's x-row
  const int pbase = blockIdx.x * PART_COLS;
  float* q = &qmem[w][lane * QSTR];

  // x fragments (B-operand: B[k = quad*8+j + 32ks][n = l15]) + exact fp32 norm
  v8h bx0, bx1;
  float xn;
  {
    const float* xr = x + (size_t)row * DIM;
    const float4* xp0 = (const float4*)(xr + quad * 8);
    float4 a0 = xp0[0], a1 = xp0[1];
    const float4* xp1 = (const float4*)(xr + 32 + quad * 8);
    float4 c0 = xp1[0], c1 = xp1[1];
    v8h h0, h1;
    h0[0]=(_Float16)a0.x; h0[1]=(_Float16)a0.y; h0[2]=(_Float16)a0.z; h0[3]=(_Float16)a0.w;
    h0[4]=(_Float16)a1.x; h0[5]=(_Float16)a1.y; h0[6]=(_Float16)a1.z; h0[7]=(_Float16)a1.w;
    h1[0]=(_Float16)c0.x; h1[1]=(_Float16)c0.y; h1[2]=(_Float16)c0.z; h1[3]=(_Float16)c0.w;
    h1[4]=(_Float16)c1.x; h1[5]=(_Float16)c1.y; h1[6]=(_Float16)c1.z; h1[7]=(_Float16)c1.w;
    bx0 = h0; bx1 = h1;
    float s = a0.x*a0.x + a0.y*a0.y + a0.z*a0.z + a0.w*a0.w
            + a1.x*a1.x + a1.y*a1.y + a1.z*a1.z + a1.w*a1.w
            + c0.x*c0.x + c0.y*c0.y + c0.z*c0.z + c0.w*c0.w
            + c1.x*c1.x + c1.y*c1.y + c1.z*c1.z + c1.w*c1.w;
    s += __shfl_xor(s, 16);   // each quad holds a disjoint 16 of the 64 k's
    s += __shfl_xor(s, 32);
    xn = s;
  }

  float lst[KSEL];
#pragma unroll
  for (int i = 0; i < KSEL; ++i) lst[i] = __builtin_inff();
  float lmax = __builtin_inff();
  float thr  = __builtin_inff();
  int qcnt = 0;

  for (int c = 0; c < NCHUNK; ++c) {
    const int cb = pbase + c * CHUNK;
    __syncthreads();   // Bs free
    {
      // 2 threads per col; each stages a contiguous 32-f16 (64 B) half-row
      int col = tid >> 1, hf = tid & 1;
      const uint4* src = (const uint4*)(B16 + (size_t)(cb + col) * DIM + hf * 32);
      uint4 v0 = src[0], v1 = src[1], v2 = src[2], v3 = src[3];
      uint4* dst = (uint4*)(Bs + col * BSTRIDE + hf * 32);
      dst[0] = v0; dst[1] = v1; dst[2] = v2; dst[3] = v3;
      if (tid < CHUNK) bns[tid] = bnorm[cb + tid];
    }
    __syncthreads();   // staged

#pragma unroll
    for (int mt = 0; mt < 8; ++mt) {
      v8h a0 = *(const v8h*)(Bs + (mt * 16 + l15) * BSTRIDE + quad * 8);
      v8h a1 = *(const v8h*)(Bs + (mt * 16 + l15) * BSTRIDE + 32 + quad * 8);
      v4f acc = (v4f)(0.0f);
      acc = __builtin_amdgcn_mfma_f32_16x16x32_f16(a0, bx0, acc, 0, 0, 0);
      acc = __builtin_amdgcn_mfma_f32_16x16x32_f16(a1, bx1, acc, 0, 0, 0);
      float4 bn4 = *(const float4*)&bns[mt * 16 + quad * 4];
#pragma unroll
      for (int reg = 0; reg < 4; ++reg) {
        float bn = (reg == 0) ? bn4.x : (reg == 1) ? bn4.y : (reg == 2) ? bn4.z : bn4.w;
        float d2 = fmaf(acc[reg], -2.0f, xn + bn);
        d2 = fmaxf(d2, 0.0f);
        if (d2 <= thr) { q[qcnt] = d2; ++qcnt; }   // exec-masked push, no branch
      }
    }

    // lane-private drain (wave-uniform skip when all queues empty)
    if (__ballot(qcnt > 0)) {
      for (int i = 0; i < qcnt; ++i) {
        float v = q[i];
        if (v < lmax) ins11(v, lst, lmax);
      }
      qcnt = 0;
      // tighten shared threshold: min over the 4 quads holding this row
      float t = fminf(lmax, __shfl_xor(lmax, 16));
      thr = fminf(t, __shfl_xor(t, 32));
    }
  }

  // merge the 4 quads' lists (disjoint col subsets of the same row) in-register
#pragma unroll
  for (int s = 16; s <= 32; s <<= 1) {
    float other[KSEL];
#pragma unroll
    for (int j = 0; j < KSEL; ++j) other[j] = __shfl_xor(lst[j], s);
#pragma unroll
    for (int j = 0; j < KSEL; ++j)
      if (other[j] < lmax) ins11(other[j], lst, lmax);
  }

  if (quad == 0) {   // one writer per row: cand layout [row][part][k]
    float* dst = cand + (size_t)row * (PPART * KSEL) + blockIdx.x * KSEL;
#pragma unroll
    for (int i = 0; i < KSEL; ++i) dst[i] = lst[i];
  }
}

// ---------------- merge: wave per row, 704 = 64 lanes x 11 ----------------
__global__ __launch_bounds__(256) void k_merge(const float* __restrict__ cand,
                                               float* __restrict__ out) {
  int w = threadIdx.x >> 6, lane = threadIdx.x & 63;
  int row = blockIdx.x * 4 + w;
  const float* src = cand + (size_t)row * (PPART * KSEL) + lane * KSEL;
  float lst[KSEL];
#pragma unroll
  for (int i = 0; i < KSEL; ++i) lst[i] = src[i];
  float a = fmaxf(fmaxf(lst[0], lst[1]), fmaxf(lst[2], lst[3]));
  float b = fmaxf(fmaxf(lst[4], lst[5]), fmaxf(lst[6], lst[7]));
  float c = fmaxf(fmaxf(lst[8], lst[9]), lst[10]);
  float lmax = fmaxf(fmaxf(a, b), c);
#pragma unroll
  for (int s = 1; s <= 32; s <<= 1) {
    float other[KSEL];
#pragma unroll
    for (int j = 0; j < KSEL; ++j) other[j] = __shfl_xor(lst[j], s);
#pragma unroll
    for (int j = 0; j < KSEL; ++j)
      if (other[j] < lmax) ins11(other[j], lst, lmax);
  }
  if (lane == 0) {
    float vmin = lst[0];
#pragma unroll
    for (int j = 1; j < KSEL; ++j) vmin = fminf(vmin, lst[j]);
    float s = 0.0f;
#pragma unroll
    for (int j = 0; j < KSEL; ++j) s += sqrtf(lst[j]);
    s -= sqrtf(vmin);                 // drop the self-match
    out[row] = log1pf(s * 0.1f);      // mean over k=10, log1p
  }
}

extern "C" void kernel_launch(void* const* d_in, const int* in_sizes, int n_in,
                              void* d_out, int out_size, void* d_ws, size_t ws_size,
                              hipStream_t stream) {
  (void)in_sizes; (void)n_in; (void)out_size; (void)ws_size;
  const float* x   = (const float*)d_in[0];   // 2048 x 64
  const float* buf = (const float*)d_in[1];   // 131072 x 64
  float* out = (float*)d_out;

  char* ws = (char*)d_ws;
  _Float16* B16 = (_Float16*)ws;                       // 16,777,216 B
  float* bnorm  = (float*)(ws + 16777216);             //    524,288 B
  float* cand   = (float*)(ws + 17301504);             //  5,767,168 B

  k_prep_b<<<dim3(2048), dim3(256), 0, stream>>>(buf, B16, bnorm);
  k_main<<<dim3(PPART, NR / ROWS_PER_BLOCK), dim3(256), 0, stream>>>(x, B16, bnorm, cand);
  k_merge<<<dim3(NR / 4), dim3(256), 0, stream>>>(cand, out);
}